// Round 5
// baseline (60.648 us; speedup 1.0000x reference)
//
#include <hip/hip_runtime.h>
#include <hip/hip_bf16.h>

#define BB 16
#define LCTX 2048
#define DDIM 1024
#define QDIM 1024
#define HDIM 256
#define NEGV -10000.0f

typedef __attribute__((ext_vector_type(8))) short short8;
typedef __attribute__((ext_vector_type(4))) float f32x4;

__device__ inline unsigned short f2bf(float x) {
    unsigned int u = __float_as_uint(x);
    unsigned int r = (u + 0x7fffu + ((u >> 16) & 1u)) >> 16;
    return (unsigned short)r;
}

// ---------------- K1: fused prep ----------------
__global__ __launch_bounds__(256) void k_prep(const float* __restrict__ query,
                                              const float* __restrict__ W1,
                                              const float* __restrict__ b1,
                                              const float* __restrict__ v,
                                              const float* __restrict__ g,
                                              float* __restrict__ qproj,
                                              unsigned short* __restrict__ Wc_sw,
                                              float* __restrict__ w2) {
    int bid = blockIdx.x;
    if (bid < 1024) {
        int b = bid >> 6;
        int hq = bid & 63;
        int wid = threadIdx.x >> 6, lane = threadIdx.x & 63;
        int h = hq * 4 + wid;
        const float* q = query + b * QDIM;
        const float* w = W1 + (size_t)h * (DDIM + QDIM) + DDIM;
        float s = 0.f;
        #pragma unroll 4
        for (int k = lane; k < QDIM; k += 64) s += q[k] * w[k];
        #pragma unroll
        for (int o = 32; o; o >>= 1) s += __shfl_down(s, o);
        if (lane == 0) qproj[b * HDIM + h] = s + b1[h];
    } else if (bid < 1280) {
        int h = bid - 1024;
        const float* src = W1 + (size_t)h * (DDIM + QDIM);
        int hx = h & 7;
        for (int d = threadIdx.x; d < DDIM; d += 256) {
            int kt = d >> 6;
            int s  = (d >> 3) & 7;
            int dl = d & 7;
            int dp = (kt << 6) + ((s ^ hx) << 3) + dl;
            Wc_sw[h * DDIM + dp] = f2bf(src[d]);
        }
    } else {
        __shared__ float red[256];
        float vv = (threadIdx.x < HDIM) ? v[threadIdx.x] : 0.f;
        red[threadIdx.x] = vv * vv;
        __syncthreads();
        for (int o = 128; o; o >>= 1) {
            if (threadIdx.x < o) red[threadIdx.x] += red[threadIdx.x + o];
            __syncthreads();
        }
        float nrm = sqrtf(red[0]);
        if (threadIdx.x < HDIM) w2[threadIdx.x] = g[0] * vv / nrm;
    }
}

// ---------------- K2: wave-autonomous ctx stream ----------------
// Block = 64 ctx rows; wave w owns rows [w*16, w*16+16) x ALL 256 h.
// A (ctx): global -> VGPR (dbuf reg sets) -> bf16 frags. Never in LDS, never
//          gated by a barrier; compiler inserts counted vmcnt for the reg deps.
// B (W):   shared dbuf LDS tile, each wave stages its quarter via gload_lds;
//          own-wave vmcnt(4) + raw s_barrier per iter (W is L2-hot, 1 iter early).
// Ledger (per wave): entry queue = [W(t).8, A(t).4]; vmcnt(4) drains W(t);
//          barrier; issue W(t+1).8 + A(t+1).4; compiler drains A(t) for cvt.
__global__ __launch_bounds__(256, 2) void k_score(const float* __restrict__ ctx,
                                                  const unsigned short* __restrict__ Wc_sw,
                                                  const float* __restrict__ qproj,
                                                  const float* __restrict__ w2,
                                                  const float* __restrict__ b2p,
                                                  const int* __restrict__ mask,
                                                  float* __restrict__ e_ws,
                                                  float* __restrict__ esum_ws,
                                                  float* __restrict__ part) {
    __shared__ unsigned short Wt[2][256 * 64];   // 64 KB dbuf
    __shared__ float sbe[64];
    int tid = threadIdx.x;
    int wid = tid >> 6, lane = tid & 63;
    int hl = lane & 15, lhi = lane >> 4;
    int row0 = blockIdx.x * 64;
    int b = row0 >> 11;

    f32x4 acc[16];
    #pragma unroll
    for (int ht = 0; ht < 16; ht++) acc[ht] = (f32x4){0.f, 0.f, 0.f, 0.f};

    // per-lane A base: row = row0 + wid*16 + hl, k-offset lhi*8
    const float* abase = ctx + (size_t)(row0 + wid * 16 + hl) * DDIM + lhi * 8;

    float4 r0, r1, r2, r3, s0, s1, s2, s3;

#define STAGE_W(BUF, KT) do { \
    _Pragma("unroll") \
    for (int i_ = 0; i_ < 8; i_++) { \
        const unsigned short* gsrc_ = Wc_sw + (size_t)(wid * 64 + i_ * 8 + (lane >> 3)) * DDIM + (KT) * 64 + (lane & 7) * 8; \
        __builtin_amdgcn_global_load_lds( \
            (const __attribute__((address_space(1))) unsigned int*)gsrc_, \
            (__attribute__((address_space(3))) unsigned int*)(&Wt[BUF][(wid * 64 + i_ * 8) * 64]), \
            16, 0, 0); \
    } } while (0)

#define ISSUE_A(KT, R0, R1, R2, R3) do { \
    const float* p_ = abase + (KT) * 64; \
    R0 = *(const float4*)(p_ + 0);  R1 = *(const float4*)(p_ + 4); \
    R2 = *(const float4*)(p_ + 32); R3 = *(const float4*)(p_ + 36); } while (0)

#define BODY(KT, R0, R1, R2, R3, S0, S1, S2, S3) do { \
    asm volatile("s_waitcnt vmcnt(4)" ::: "memory"); \
    __builtin_amdgcn_s_barrier(); \
    __builtin_amdgcn_sched_barrier(0); \
    if ((KT) < 15) { \
        STAGE_W(((KT) + 1) & 1, (KT) + 1); \
        ISSUE_A((KT) + 1, S0, S1, S2, S3); \
        __builtin_amdgcn_sched_barrier(0); \
    } \
    short8 af0_ = { (short)f2bf(R0.x), (short)f2bf(R0.y), (short)f2bf(R0.z), (short)f2bf(R0.w), \
                    (short)f2bf(R1.x), (short)f2bf(R1.y), (short)f2bf(R1.z), (short)f2bf(R1.w) }; \
    short8 af1_ = { (short)f2bf(R2.x), (short)f2bf(R2.y), (short)f2bf(R2.z), (short)f2bf(R2.w), \
                    (short)f2bf(R3.x), (short)f2bf(R3.y), (short)f2bf(R3.z), (short)f2bf(R3.w) }; \
    __builtin_amdgcn_s_setprio(1); \
    _Pragma("unroll") \
    for (int ht_ = 0; ht_ < 16; ht_++) { \
        short8 bf0_ = *(const short8*)(&Wt[(KT) & 1][(ht_ * 16 + hl) * 64 + ((lhi ^ (hl & 7)) << 3)]); \
        acc[ht_] = __builtin_amdgcn_mfma_f32_16x16x32_bf16(af0_, bf0_, acc[ht_], 0, 0, 0); \
    } \
    _Pragma("unroll") \
    for (int ht_ = 0; ht_ < 16; ht_++) { \
        short8 bf1_ = *(const short8*)(&Wt[(KT) & 1][(ht_ * 16 + hl) * 64 + (((4 + lhi) ^ (hl & 7)) << 3)]); \
        acc[ht_] = __builtin_amdgcn_mfma_f32_16x16x32_bf16(af1_, bf1_, acc[ht_], 0, 0, 0); \
    } \
    __builtin_amdgcn_s_setprio(0); } while (0)

    // ---- prologue: queue = [W(0).8, A(0).4] ----
    STAGE_W(0, 0);
    ISSUE_A(0, r0, r1, r2, r3);
    __builtin_amdgcn_sched_barrier(0);

    BODY(0,  r0, r1, r2, r3, s0, s1, s2, s3);
    BODY(1,  s0, s1, s2, s3, r0, r1, r2, r3);
    BODY(2,  r0, r1, r2, r3, s0, s1, s2, s3);
    BODY(3,  s0, s1, s2, s3, r0, r1, r2, r3);
    BODY(4,  r0, r1, r2, r3, s0, s1, s2, s3);
    BODY(5,  s0, s1, s2, s3, r0, r1, r2, r3);
    BODY(6,  r0, r1, r2, r3, s0, s1, s2, s3);
    BODY(7,  s0, s1, s2, s3, r0, r1, r2, r3);
    BODY(8,  r0, r1, r2, r3, s0, s1, s2, s3);
    BODY(9,  s0, s1, s2, s3, r0, r1, r2, r3);
    BODY(10, r0, r1, r2, r3, s0, s1, s2, s3);
    BODY(11, s0, s1, s2, s3, r0, r1, r2, r3);
    BODY(12, r0, r1, r2, r3, s0, s1, s2, s3);
    BODY(13, s0, s1, s2, s3, r0, r1, r2, r3);
    BODY(14, r0, r1, r2, r3, s0, s1, s2, s3);
    BODY(15, s0, s1, s2, s3, r0, r1, r2, r3);

    // ---- epilogue: tanh + w2 dot; reduce over hl (16 lanes) = full 256 h ----
    float qp[16], wv[16];
    #pragma unroll
    for (int ht = 0; ht < 16; ht++) {
        qp[ht] = qproj[b * HDIM + ht * 16 + hl];
        wv[ht] = w2[ht * 16 + hl];
    }
    float bias2 = b2p[0];
    #pragma unroll
    for (int r = 0; r < 4; r++) {
        float partial = 0.f;
        #pragma unroll
        for (int ht = 0; ht < 16; ht++) {
            float x = acc[ht][r] + qp[ht];
            x = fminf(fmaxf(x, -15.f), 15.f);
            float e2 = __expf(2.f * x);
            partial += (e2 - 1.f) / (e2 + 1.f) * wv[ht];
        }
        #pragma unroll
        for (int o = 1; o < 16; o <<= 1) partial += __shfl_xor(partial, o);
        if (hl == 0) {
            int lrow = wid * 16 + lhi * 4 + r;
            int grow = row0 + lrow;
            float s = partial + bias2;
            float e = (mask[b * 2048 + (grow & 2047)] == 1) ? 0.f : __expf(s);
            e_ws[grow] = e;
            sbe[lrow] = e;
        }
    }
    __syncthreads();

    if (tid < 64) {
        float tot = sbe[tid];
        #pragma unroll
        for (int o = 32; o; o >>= 1) tot += __shfl_down(tot, o);
        if (tid == 0) esum_ws[blockIdx.x] = tot;
    }

    // ---- partial GEMV: part[bid][d] = sum_l e_l * ctx[row0+l][d] (tile L2/L3-hot) ----
    {
        int d0 = tid * 4;
        const float* cb = ctx + (size_t)row0 * DDIM + d0;
        float4 a = {0.f, 0.f, 0.f, 0.f};
        #pragma unroll 8
        for (int l = 0; l < 64; l++) {
            float el = sbe[l];
            float4 cc = *(const float4*)(cb + (size_t)l * DDIM);
            a.x += el * cc.x; a.y += el * cc.y; a.z += el * cc.z; a.w += el * cc.w;
        }
        *(float4*)(part + (size_t)blockIdx.x * DDIM + d0) = a;
    }
}

// ---------------- K3: normalize -> out_exp, out_p ----------------
__global__ __launch_bounds__(256) void k_norm(const float* __restrict__ e_ws,
                                              const float* __restrict__ esum_ws,
                                              const float* __restrict__ part,
                                              float* __restrict__ out_exp,
                                              float* __restrict__ out_p) {
    int b = blockIdx.x, dc = blockIdx.y;
    int tid = threadIdx.x;
    float se = 0.f;
    #pragma unroll
    for (int j = 0; j < 32; j++) se += esum_ws[b * 32 + j];
    float inv = 1.f / se;
    if (tid < 128) {
        int d = dc * 128 + tid;
        float s = 0.f;
        #pragma unroll
        for (int j = 0; j < 32; j++) s += part[(size_t)(b * 32 + j) * DDIM + d];
        out_exp[b * DDIM + d] = s * inv;
    }
    int l = dc * 256 + tid;
    out_p[b * LCTX + l] = e_ws[b * LCTX + l] * inv;
}

extern "C" void kernel_launch(void* const* d_in, const int* in_sizes, int n_in,
                              void* d_out, int out_size, void* d_ws, size_t ws_size,
                              hipStream_t stream) {
    const float* ctx   = (const float*)d_in[0];
    const float* query = (const float*)d_in[1];
    const int*   mask  = (const int*)d_in[2];
    const float* W1    = (const float*)d_in[3];
    const float* b1    = (const float*)d_in[4];
    const float* v     = (const float*)d_in[5];
    const float* g     = (const float*)d_in[6];
    const float* b2    = (const float*)d_in[7];
    float* out_exp = (float*)d_out;              // [16,1024]
    float* out_p   = (float*)d_out + 16384;      // [16,2048]

    char* ws = (char*)d_ws;
    unsigned short* Wc_sw = (unsigned short*)ws;          // 512 KB
    float* qproj = (float*)(ws + 524288);                 // 16 KB
    float* w2    = (float*)(ws + 540672);                 // 1 KB
    float* e_ws  = (float*)(ws + 541696);                 // 128 KB (16x2048)
    float* esum  = (float*)(ws + 672768);                 // 2 KB  (512)
    float* part  = (float*)(ws + 674816);                 // 2 MB  (512x1024)

    k_prep <<<dim3(1281),   256, 0, stream>>>(query, W1, b1, v, g, qproj, Wc_sw, w2);
    k_score<<<dim3(512),    256, 0, stream>>>(ctx, Wc_sw, qproj, w2, b2, mask, e_ws, esum, part);
    k_norm <<<dim3(16, 8),  256, 0, stream>>>(e_ws, esum, part, out_exp, out_p);
}